// Round 2
// baseline (68.788 us; speedup 1.0000x reference)
//
#include <hip/hip_runtime.h>

// TropConv2D: out[b,ho,wo,f] = max_k(patch_k + w[k,f]) - min_k(patch_k + w[k,f])
// x: (8,32,32,32) f32 NHWC, w: (288,64) f32 (72 KB), out: (8,30,30,64) f32
// k = (i*3 + j)*32 + c   (TF extract_patches ordering)
//
// v7: scalar-pipe broadcast, SINGLE-WAIT edition. v6 (per-ij s_load +
//   lgkmcnt(0) every iteration) was +2us vs v5: SMEM is out-of-order so the
//   per-ij full drain serialized ~300cyc L2 latency 9x per wave, and
//   cur/nxt double-buffer tied ~90 SGPRs (spill risk). Fix: split channels
//   16 ways (16 waves x 2ch, block=1024) so the wave's ENTIRE patch
//   footprint is 3 rows x 10 cols x 8B = 30 s_load_dwordx2 = 60 SGPRs,
//   all issued upfront, ONE lgkmcnt(0), zero rotation copies. Main loop is
//   then pure VALU: 288 instrs/wave (= v5's total op count, the 3.4us
//   VALU floor), weights prefetched per-lane via VMEM.
//   - Consumers tied to the wait via "+s" empty-asm per row (rule-#18
//     hazard: data-dep prevents hoisting compute above the wait; v6
//     verified this pattern exact, absmax 0).
//   - q=3 clamps scalar col offsets to col 31; clamped px>=6 discarded.
//   - 16-way combine over 64KB LDS: 2 blocks/CU x 16 waves = 32 waves/CU
//     (HW cap) -> LDS costs no occupancy. max/min associative -> exact.

#define C_IN 32
#define NF 64
#define H_OUT 30
#define W_OUT 30
#define W_IN 32
#define NWAVE 16

typedef __attribute__((ext_vector_type(2))) float f32x2;

static __device__ __forceinline__ float max3f(float a, float b, float c) {
    return fmaxf(fmaxf(a, b), c);
}
static __device__ __forceinline__ float min3f(float a, float b, float c) {
    return fminf(fminf(a, b), c);
}

// scalar 8B load: base (SGPR pair) + byte offset (SGPR)
static __device__ __forceinline__ f32x2 sload8(const float* base, unsigned off_bytes) {
    f32x2 r;
    asm volatile("s_load_dwordx2 %0, %1, %2"
                 : "=s"(r)
                 : "s"(base), "s"(off_bytes));
    return r;
}

__global__ __launch_bounds__(1024) void tropconv_kernel(
    const float* __restrict__ x,
    const float* __restrict__ w,
    float* __restrict__ out) {
    const int bx = blockIdx.x;            // 0..959
    const int q = bx & 3;                 // row quarter
    const int bho = bx >> 2;              // b*30 + ho
    const int b = bho / H_OUT;
    const int ho = bho - b * H_OUT;
    const int tid = threadIdx.x;
    const int lane = tid & 63;            // filter index
    // wave-uniform so all patch address math stays on the scalar pipe
    const int wave = __builtin_amdgcn_readfirstlane(tid >> 6);  // 0..15, 2-ch slice

    const int col0 = q * 8;
    const int npx = (q == 3) ? 6 : 8;

    __shared__ float pmx[NWAVE][8][NF];   // 32 KB partial max
    __shared__ float pmn[NWAVE][8][NF];   // 32 KB partial min

    // column byte offsets, clamped so q==3 never reads past col 31 (the
    // clamped loads feed px>=npx which the combine discards)
    const int mcc = 31 - col0;            // >= 15 for q<3, == 7 for q==3
    unsigned coff[10];
    #pragma unroll
    for (int c = 0; c < 10; ++c) {
        const int cc = (c < mcc) ? c : mcc;
        coff[c] = (unsigned)((col0 + cc) * C_IN * 4);
    }

    // scalar row bases: row (b*32+ho+r), col 0, channel slice wave*2
    const float* rbase = x + (size_t)((b * 32 + ho) * W_IN) * C_IN + wave * 2;

    // ---- issue ALL patch loads upfront (30 x s_load_dwordx2, one wait) ----
    f32x2 rc[3][10];
    #pragma unroll
    for (int r = 0; r < 3; ++r) {
        const float* rb = rbase + (size_t)r * W_IN * C_IN;
        #pragma unroll
        for (int c = 0; c < 10; ++c) rc[r][c] = sload8(rb, coff[c]);
    }

    // ---- weight prefetch (per-lane VMEM, L2-resident 72 KB) ----
    // w[(ij*32 + wave*2 + t)*64 + lane], t = 0,1
    const float* __restrict__ wbase = w + (size_t)(wave * 2) * NF + lane;
    float w0[9], w1[9];
    #pragma unroll
    for (int ij = 0; ij < 9; ++ij) {
        w0[ij] = wbase[(ij * C_IN) * NF];
        w1[ij] = wbase[(ij * C_IN + 1) * NF];
    }

    float mx[8], mn[8];
    #pragma unroll
    for (int t = 0; t < 8; ++t) { mx[t] = -INFINITY; mn[t] = INFINITY; }

    // single drain of all 30 scalar loads; tie consumers so the compiler
    // cannot hoist the VALU uses above the wait (SMEM is out-of-order).
    asm volatile("s_waitcnt lgkmcnt(0)");
    #pragma unroll
    for (int r = 0; r < 3; ++r) {
        asm volatile(""
                     : "+s"(rc[r][0]), "+s"(rc[r][1]), "+s"(rc[r][2]),
                       "+s"(rc[r][3]), "+s"(rc[r][4]), "+s"(rc[r][5]),
                       "+s"(rc[r][6]), "+s"(rc[r][7]), "+s"(rc[r][8]),
                       "+s"(rc[r][9]));
    }

    // ---- pure-VALU main loop: 9 ij x 8 px x (2 add + max3 + min3) ----
    #pragma unroll
    for (int ij = 0; ij < 9; ++ij) {
        const int i = ij / 3;
        const int j = ij - i * 3;
        #pragma unroll
        for (int px = 0; px < 8; ++px) {
            const f32x2 p = rc[i][j + px];
            float s0 = p.x + w0[ij];
            float s1 = p.y + w1[ij];
            mx[px] = max3f(s0, s1, mx[px]);
            mn[px] = min3f(s0, s1, mn[px]);
        }
    }

    #pragma unroll
    for (int px = 0; px < 8; ++px) {
        pmx[wave][px][lane] = mx[px];
        pmn[wave][px][lane] = mn[px];
    }
    __syncthreads();

    // ---- cross-wave combine (exact: max/min associative) ----
    const int nout = npx * NF;            // 512 or 384
    if (tid < nout) {
        const int px = tid >> 6;
        const int f = tid & 63;
        float a = pmx[0][px][f];
        float m = pmn[0][px][f];
        #pragma unroll
        for (int ww = 1; ww < NWAVE; ++ww) {
            a = fmaxf(a, pmx[ww][px][f]);
            m = fminf(m, pmn[ww][px][f]);
        }
        out[((size_t)bho * W_OUT + (col0 + px)) * NF + f] = a - m;
    }
}

extern "C" void kernel_launch(void* const* d_in, const int* in_sizes, int n_in,
                              void* d_out, int out_size, void* d_ws, size_t ws_size,
                              hipStream_t stream) {
    const float* x = (const float*)d_in[0];   // 8*32*32*32
    const float* w = (const float*)d_in[1];   // 288*64
    float* out = (float*)d_out;               // 8*30*30*64

    dim3 grid(8 * H_OUT * 4);                 // 960 blocks
    dim3 block(1024);
    tropconv_kernel<<<grid, block, 0, stream>>>(x, w, out);
}

// Round 3
// 63.801 us; speedup vs baseline: 1.0782x; 1.0782x over previous
//
#include <hip/hip_runtime.h>

// TropConv2D: out[b,ho,wo,f] = max_k(patch_k + w[k,f]) - min_k(patch_k + w[k,f])
// x: (8,32,32,32) f32 NHWC, w: (288,64) f32 (72 KB), out: (8,30,30,64) f32
// k = (i*3 + j)*32 + c   (TF extract_patches ordering)
//
// v8: v5 structure (LDS broadcast was the best of v5/v6/v7 -- both scalar-pipe
//   variants regressed: SMEM/K$ throughput < LDS pipe for this shape), with
//   the LDS issue count cut ~2.3x. v5's per-CU arithmetic: LDS pipe ~31K cyc
//   (72 b128/wave: the 3-tap window re-reads each staged col 3x) vs VALU
//   ~8.6K cyc -> LDS-issue-bound. Fix: slide the window in REGISTERS --
//   iterate the 30 unique (row,col) x-vectors, read each ONCE (b128), apply
//   its <=3 valid (j, px=cc-j) taps immediately. Same 576 VALU ops/wave,
//   same max/min associativity (exact, absmax 0).
//   - partial store packed as ds_write_b64 {mx,mn} (16->8 instrs/wave)
//   - combine reads b128 over filter-pairs (128->32 wave-instrs/block)
//   - r-loop NOT unrolled: keeps 12 (not 36) weights live, VGPR <=64,
//     8 waves/SIMD (the v3/v4 spill lesson).
//   - q=3: cols 8,9 of the tile are unstaged junk; they only feed px>=6,
//     which the combine discards (npx=6). Same discard logic as v5.

#define C_IN 32
#define NF 64
#define H_OUT 30
#define W_OUT 30
#define W_IN 32

static __device__ __forceinline__ float max3f(float a, float b, float c) {
    return fmaxf(fmaxf(a, b), c);
}
static __device__ __forceinline__ float min3f(float a, float b, float c) {
    return fminf(fminf(a, b), c);
}

__global__ __launch_bounds__(512) void tropconv_kernel(
    const float* __restrict__ x,
    const float* __restrict__ w,
    float* __restrict__ out) {
    const int bx = blockIdx.x;            // 0..959
    const int q = bx & 3;                 // row quarter
    const int bho = bx >> 2;              // b*30 + ho
    const int b = bho / H_OUT;
    const int ho = bho - b * H_OUT;
    const int tid = threadIdx.x;
    const int lane = tid & 63;            // filter index
    const int wave = tid >> 6;            // channel-slice 0..7 (c = wave*4..+3)

    const int col0 = q * 8;
    const int npx = (q == 3) ? 6 : 8;
    const int ncols = (q == 3) ? 8 : 10;  // staged input cols (OOB-safe for q=3)

    __shared__ __align__(16) float xs[3 * 10 * C_IN];   // 3.75 KB patch tile
    __shared__ __align__(16) float pms[8][8][NF][2];    // 32 KB {max,min} partials

    // ---- Stage patch rows (contiguous NHWC segments, coalesced float4) ----
    {
        const int nf4_row = ncols * (C_IN / 4);    // 80 or 64 float4 per row
        const int total_f4 = 3 * nf4_row;          // 240 or 192 (< 512)
        if (tid < total_f4) {
            const int r = tid / nf4_row;
            const int cc = tid - r * nf4_row;
            const float4* __restrict__ src = (const float4*)(
                x + ((size_t)((b * 32 + ho + r) * W_IN + col0)) * C_IN);
            ((float4*)xs)[r * 80 + cc] = src[cc];
        }
    }

    __syncthreads();

    float mx[8], mn[8];
    #pragma unroll
    for (int t = 0; t < 8; ++t) { mx[t] = -INFINITY; mn[t] = INFINITY; }

    // weight base for this wave's channel slice: w[(r*3+j)*32 + wave*4 + cc][lane]
    const float* __restrict__ wrow = w + (size_t)(wave * 4) * NF + lane;
    const float* xrow = xs + wave * 4;

    #pragma unroll 1   // runtime r: keeps 12 weights live (not 36), VGPR <= 64
    for (int r = 0; r < 3; ++r) {
        float wr[12];                      // [j*4 + cc]
        #pragma unroll
        for (int t = 0; t < 12; ++t)
            wr[t] = wrow[((t >> 2) * C_IN + (t & 3)) * NF];

        #pragma unroll
        for (int cc = 0; cc < 10; ++cc) {  // 30 unique b128 reads total
            const float4 p = *(const float4*)(xrow + cc * C_IN);
            #pragma unroll
            for (int j = 0; j < 3; ++j) {
                const int px = cc - j;     // compile-time; 24 valid taps/row
                if (px >= 0 && px < 8) {
                    float s0 = p.x + wr[j * 4 + 0];
                    float s1 = p.y + wr[j * 4 + 1];
                    float s2 = p.z + wr[j * 4 + 2];
                    float s3 = p.w + wr[j * 4 + 3];
                    mx[px] = max3f(max3f(s0, s1, s2), s3, mx[px]);
                    mn[px] = min3f(min3f(s0, s1, s2), s3, mn[px]);
                }
            }
        }
        wrow += 3 * C_IN * NF;
        xrow += 10 * C_IN;
    }

    // ---- packed partial store: one b64 per px ----
    #pragma unroll
    for (int px = 0; px < 8; ++px) {
        float2 v; v.x = mx[px]; v.y = mn[px];
        *(float2*)&pms[wave][px][lane][0] = v;
    }
    __syncthreads();

    // ---- cross-wave combine (exact: max/min associative), b128 over f-pairs ----
    if (tid < npx * 32) {
        const int px = tid >> 5;
        const int fp = tid & 31;           // filter pair: f = 2*fp, 2*fp+1
        float4 v0 = *(const float4*)&pms[0][px][fp * 2][0];
        float a0 = v0.x, m0 = v0.y, a1 = v0.z, m1 = v0.w;
        #pragma unroll
        for (int ww = 1; ww < 8; ++ww) {
            const float4 v = *(const float4*)&pms[ww][px][fp * 2][0];
            a0 = fmaxf(a0, v.x); m0 = fminf(m0, v.y);
            a1 = fmaxf(a1, v.z); m1 = fminf(m1, v.w);
        }
        float2 o; o.x = a0 - m0; o.y = a1 - m1;
        *(float2*)&out[((size_t)bho * W_OUT + (col0 + px)) * NF + fp * 2] = o;
    }
}

extern "C" void kernel_launch(void* const* d_in, const int* in_sizes, int n_in,
                              void* d_out, int out_size, void* d_ws, size_t ws_size,
                              hipStream_t stream) {
    const float* x = (const float*)d_in[0];   // 8*32*32*32
    const float* w = (const float*)d_in[1];   // 288*64
    float* out = (float*)d_out;               // 8*30*30*64

    dim3 grid(8 * H_OUT * 4);                 // 960 blocks
    dim3 block(512);
    tropconv_kernel<<<grid, block, 0, stream>>>(x, w, out);
}